// Round 2
// baseline (3828.893 us; speedup 1.0000x reference)
//
#include <hip/hip_runtime.h>
#include <stdint.h>

#define NBLK  1024
#define ROWS  32
#define PITCH 201
#define BATCH 32768

struct KParams {
  const float* prev_state; const float* prev_action; const float* prev_belief;
  const float* observation; const float* nonterm;
  const float* W_sa; const float* b_sa;
  const float* W_ir; const float* b_ir;
  const float* W_iz; const float* b_iz;
  const float* W_in; const float* b_in;
  const float* W_hr; const float* W_hz; const float* W_hn; const float* b_hn;
  const float* W_bp; const float* b_bp; const float* W_sp; const float* b_sp;
  const float* W_bq; const float* b_bq; const float* W_sq; const float* b_sq;
  float* out;
};

__device__ __forceinline__ float4 ld4(const float* p){ return *(const float4*)p; }
__device__ __forceinline__ float4 fma4(float a, float4 w, float4 c){
  c.x = fmaf(a, w.x, c.x); c.y = fmaf(a, w.y, c.y);
  c.z = fmaf(a, w.z, c.z); c.w = fmaf(a, w.w, c.w); return c;
}
__device__ __forceinline__ float4 relu4(float4 v){
  v.x = fmaxf(v.x, 0.f); v.y = fmaxf(v.y, 0.f);
  v.z = fmaxf(v.z, 0.f); v.w = fmaxf(v.w, 0.f); return v;
}
__device__ __forceinline__ float sigmf_(float x){ return 1.f / (1.f + expf(-x)); }
__device__ __forceinline__ float softplusf_(float x){
  return fmaxf(x, 0.f) + log1pf(expf(-fabsf(x)));
}
__device__ __forceinline__ uint32_t rotl32(uint32_t x, int r){ return (x << r) | (x >> (32 - r)); }

// Threefry-2x32, 20 rounds, key = PRNGKey(42) = (0, 42). Matches jax exactly.
__device__ __forceinline__ void threefry2x32_k42(uint32_t x0, uint32_t x1,
                                                 uint32_t& o0, uint32_t& o1){
  const uint32_t k0 = 0u, k1 = 42u, k2 = 0u ^ 42u ^ 0x1BD11BDAu;
  x0 += k0; x1 += k1;
#define TF_R(rot) { x0 += x1; x1 = rotl32(x1, rot); x1 ^= x0; }
  TF_R(13) TF_R(15) TF_R(26) TF_R(6)  x0 += k1; x1 += k2 + 1u;
  TF_R(17) TF_R(29) TF_R(16) TF_R(24) x0 += k2; x1 += k0 + 2u;
  TF_R(13) TF_R(15) TF_R(26) TF_R(6)  x0 += k0; x1 += k1 + 3u;
  TF_R(17) TF_R(29) TF_R(16) TF_R(24) x0 += k1; x1 += k2 + 4u;
  TF_R(13) TF_R(15) TF_R(26) TF_R(6)  x0 += k2; x1 += k0 + 5u;
#undef TF_R
  o0 = x0; o1 = x1;
}

// XLA's ErfInv f32 (Giles) — matches lax.erf_inv up to fma rounding.
__device__ __forceinline__ float jax_erfinv(float x){
  float w = -log1pf(-x * x);
  float p;
  if (w < 5.0f) {
    w -= 2.5f;
    p = 2.81022636e-08f;
    p = fmaf(p, w, 3.43273939e-07f);
    p = fmaf(p, w, -3.5233877e-06f);
    p = fmaf(p, w, -4.39150654e-06f);
    p = fmaf(p, w, 0.00021858087f);
    p = fmaf(p, w, -0.00125372503f);
    p = fmaf(p, w, -0.00417768164f);
    p = fmaf(p, w, 0.246640727f);
    p = fmaf(p, w, 1.50140941f);
  } else {
    w = sqrtf(w) - 3.0f;
    p = -0.000200214257f;
    p = fmaf(p, w, 0.000100950558f);
    p = fmaf(p, w, 0.00134934322f);
    p = fmaf(p, w, -0.00367342844f);
    p = fmaf(p, w, 0.00573950773f);
    p = fmaf(p, w, -0.0076224613f);
    p = fmaf(p, w, 0.00943887047f);
    p = fmaf(p, w, 1.00167406f);
    p = fmaf(p, w, 2.83297682f);
  }
  return p * x;
}

// jax.random.normal(key(42), (1, B, 100)) element j — PARTITIONABLE threefry
// (jax_threefry_partitionable=True default): counter = uint64 j, split into
// (hi=j>>32=0, lo=j), one threefry block per element, 32-bit out = o0 ^ o1.
__device__ __forceinline__ float jax_normal_at(uint32_t j){
  uint32_t o0, o1;
  threefry2x32_k42(0u, j, o0, o1);
  uint32_t bits = o0 ^ o1;
  const float lo = -0.99999994f;    // nextafter(-1, 0)
  float f = __uint_as_float((bits >> 9) | 0x3f800000u) - 1.0f;  // [0,1)
  float fm = f * 1.99999994f;       // separate mul+add: match XLA HLO (no fma)
  float u = fmaxf(lo, fm + lo);
  return 1.41421356f * jax_erfinv(u);  // sqrt(2) in fp32
}

__global__ void __launch_bounds__(256) rssm_fused(KParams p)
{
  __shared__ float sA[ROWS * PITCH];  // prev_belief -> new_belief
  __shared__ float sH[ROWS * PITCH];  // [s,a] staging -> h -> hp -> hq

  const int tid  = threadIdx.x;
  const int r    = tid & 31;          // row within tile
  const int g    = tid >> 5;          // col-group 0..7 (float4 groups == g mod 8)
  const int row0 = blockIdx.x * ROWS;
  const int grow = row0 + r;
  const int ng   = (g < 2) ? 7 : 6;   // # of float4 groups out of 50 (uniform per wave)

  // ---- stage inputs: [s*nt, a] -> sH(132 cols), prev_belief -> sA(200 cols)
  for (int idx = tid; idx < ROWS * 132; idx += 256) {
    int rr = idx / 132, cc = idx - rr * 132;
    float v;
    if (cc < 100) v = p.prev_state[(row0 + rr) * 100 + cc] * p.nonterm[row0 + rr];
    else          v = p.prev_action[(row0 + rr) * 32 + (cc - 100)];
    sH[rr * PITCH + cc] = v;
  }
  for (int idx = tid; idx < ROWS * 200; idx += 256) {
    int rr = idx / 200, cc = idx - rr * 200;
    sA[rr * PITCH + cc] = p.prev_belief[(row0 + rr) * 200 + cc];
  }
  __syncthreads();

  // ---- h = relu([s,a] @ W_sa + b_sa)
  float4 acc[7];
  #pragma unroll
  for (int i = 0; i < 7; ++i) if (i < ng) acc[i] = ld4(p.b_sa + 4 * (g + 8 * i));
  #pragma unroll 1
  for (int k = 0; k < 132; ++k) {
    float xv = sH[r * PITCH + k];
    const float4* w = (const float4*)(p.W_sa + k * 200);
    #pragma unroll
    for (int i = 0; i < 7; ++i) if (i < ng) acc[i] = fma4(xv, w[g + 8 * i], acc[i]);
  }
  __syncthreads();                    // all staging reads of sH done
  #pragma unroll
  for (int i = 0; i < 7; ++i) if (i < ng) {
    float4 h = relu4(acc[i]);
    int c = 4 * (g + 8 * i);
    sH[r * PITCH + c + 0] = h.x; sH[r * PITCH + c + 1] = h.y;
    sH[r * PITCH + c + 2] = h.z; sH[r * PITCH + c + 3] = h.w;
  }
  __syncthreads();

  // ---- GRU: r = sig(xWir+bir+hWhr), z = sig(xWiz+biz+hWhz),
  //           n = tanh(xWin+bin + r*(hWhn+bhn)), nb = (1-z)n + zh
  float4 ra[7], za[7], nx[7], nh[7];
  #pragma unroll
  for (int i = 0; i < 7; ++i) if (i < ng) {
    int c = 4 * (g + 8 * i);
    ra[i] = ld4(p.b_ir + c); za[i] = ld4(p.b_iz + c);
    nx[i] = ld4(p.b_in + c); nh[i] = ld4(p.b_hn + c);
  }
  #pragma unroll 1
  for (int k = 0; k < 200; ++k) {
    float xv = sA[r * PITCH + k];
    float hv = sH[r * PITCH + k];
    const float4* wir = (const float4*)(p.W_ir + k * 200);
    const float4* whr = (const float4*)(p.W_hr + k * 200);
    const float4* wiz = (const float4*)(p.W_iz + k * 200);
    const float4* whz = (const float4*)(p.W_hz + k * 200);
    const float4* win = (const float4*)(p.W_in + k * 200);
    const float4* whn = (const float4*)(p.W_hn + k * 200);
    #pragma unroll
    for (int i = 0; i < 7; ++i) if (i < ng) {
      int c4 = g + 8 * i;
      ra[i] = fma4(xv, wir[c4], ra[i]);
      ra[i] = fma4(hv, whr[c4], ra[i]);
      za[i] = fma4(xv, wiz[c4], za[i]);
      za[i] = fma4(hv, whz[c4], za[i]);
      nx[i] = fma4(xv, win[c4], nx[i]);
      nh[i] = fma4(hv, whn[c4], nh[i]);
    }
  }
  __syncthreads();                    // all GRU reads of sA/sH done
  #pragma unroll
  for (int i = 0; i < 7; ++i) if (i < ng) {
    int c = 4 * (g + 8 * i);
    float4 h4;
    h4.x = sH[r * PITCH + c + 0]; h4.y = sH[r * PITCH + c + 1];
    h4.z = sH[r * PITCH + c + 2]; h4.w = sH[r * PITCH + c + 3];
    float4 rr4, z4, n4, o;
    rr4.x = sigmf_(ra[i].x); rr4.y = sigmf_(ra[i].y); rr4.z = sigmf_(ra[i].z); rr4.w = sigmf_(ra[i].w);
    z4.x = sigmf_(za[i].x);  z4.y = sigmf_(za[i].y);  z4.z = sigmf_(za[i].z);  z4.w = sigmf_(za[i].w);
    n4.x = tanhf(fmaf(rr4.x, nh[i].x, nx[i].x));
    n4.y = tanhf(fmaf(rr4.y, nh[i].y, nx[i].y));
    n4.z = tanhf(fmaf(rr4.z, nh[i].z, nx[i].z));
    n4.w = tanhf(fmaf(rr4.w, nh[i].w, nx[i].w));
    o.x = fmaf(z4.x, h4.x - n4.x, n4.x);   // (1-z)n + zh
    o.y = fmaf(z4.y, h4.y - n4.y, n4.y);
    o.z = fmaf(z4.z, h4.z - n4.z, n4.z);
    o.w = fmaf(z4.w, h4.w - n4.w, n4.w);
    sA[r * PITCH + c + 0] = o.x; sA[r * PITCH + c + 1] = o.y;
    sA[r * PITCH + c + 2] = o.z; sA[r * PITCH + c + 3] = o.w;
    *(float4*)(p.out + (size_t)grow * 200 + c) = o;   // new_belief out
  }
  __syncthreads();                    // nb fully in sA

  // ---- prior: hp = relu(nb @ W_bp + b_bp)
  #pragma unroll
  for (int i = 0; i < 7; ++i) if (i < ng) acc[i] = ld4(p.b_bp + 4 * (g + 8 * i));
  #pragma unroll 1
  for (int k = 0; k < 200; ++k) {
    float xv = sA[r * PITCH + k];
    const float4* w = (const float4*)(p.W_bp + k * 200);
    #pragma unroll
    for (int i = 0; i < 7; ++i) if (i < ng) acc[i] = fma4(xv, w[g + 8 * i], acc[i]);
  }
  #pragma unroll
  for (int i = 0; i < 7; ++i) if (i < ng) {  // sH dead since pre-nb barrier
    float4 h = relu4(acc[i]);
    int c = 4 * (g + 8 * i);
    sH[r * PITCH + c + 0] = h.x; sH[r * PITCH + c + 1] = h.y;
    sH[r * PITCH + c + 2] = h.z; sH[r * PITCH + c + 3] = h.w;
  }
  __syncthreads();

  // ---- prior_out = relu(hp @ W_sp + b_sp); mean cols 0..99 (grp m), std 100..199 (grp m+25)
  const int nm = (g == 0) ? 4 : 3;    // float4 groups m = g+8i with m < 25
  float4 ma[4], sa4[4], eps4[4];
  #pragma unroll
  for (int i = 0; i < 4; ++i) if (i < nm) {
    int m = g + 8 * i;
    ma[i]  = ld4(p.b_sp + 4 * m);
    sa4[i] = ld4(p.b_sp + 4 * (m + 25));
  }
  #pragma unroll 1
  for (int k = 0; k < 200; ++k) {
    float hv = sH[r * PITCH + k];
    const float4* w = (const float4*)(p.W_sp + k * 200);
    #pragma unroll
    for (int i = 0; i < 4; ++i) if (i < nm) {
      int m = g + 8 * i;
      ma[i]  = fma4(hv, w[m],      ma[i]);
      sa4[i] = fma4(hv, w[m + 25], sa4[i]);
    }
  }
  {
    float* out_ps = p.out + (size_t)BATCH * 200;
    float* out_pm = p.out + (size_t)BATCH * 300;
    float* out_pd = p.out + (size_t)BATCH * 400;
    #pragma unroll
    for (int i = 0; i < 4; ++i) if (i < nm) {
      int m = g + 8 * i, c = 4 * m;
      float4 mean = relu4(ma[i]);
      float4 sraw = relu4(sa4[i]);
      float4 sd;
      sd.x = softplusf_(sraw.x) + 0.1f; sd.y = softplusf_(sraw.y) + 0.1f;
      sd.z = softplusf_(sraw.z) + 0.1f; sd.w = softplusf_(sraw.w) + 0.1f;
      uint32_t j = (uint32_t)grow * 100u + (uint32_t)c;
      eps4[i].x = jax_normal_at(j);      eps4[i].y = jax_normal_at(j + 1u);
      eps4[i].z = jax_normal_at(j + 2u); eps4[i].w = jax_normal_at(j + 3u);
      float4 st;
      st.x = fmaf(sd.x, eps4[i].x, mean.x); st.y = fmaf(sd.y, eps4[i].y, mean.y);
      st.z = fmaf(sd.z, eps4[i].z, mean.z); st.w = fmaf(sd.w, eps4[i].w, mean.w);
      *(float4*)(out_ps + (size_t)grow * 100 + c) = st;
      *(float4*)(out_pm + (size_t)grow * 100 + c) = mean;
      *(float4*)(out_pd + (size_t)grow * 100 + c) = sd;
    }
  }

  // ---- posterior: hq = relu([nb, obs] @ W_bq + b_bq) ; nb from sA, obs streamed
  #pragma unroll
  for (int i = 0; i < 7; ++i) if (i < ng) acc[i] = ld4(p.b_bq + 4 * (g + 8 * i));
  #pragma unroll 1
  for (int k = 0; k < 200; ++k) {
    float xv = sA[r * PITCH + k];
    const float4* w = (const float4*)(p.W_bq + k * 200);
    #pragma unroll
    for (int i = 0; i < 7; ++i) if (i < ng) acc[i] = fma4(xv, w[g + 8 * i], acc[i]);
  }
  {
    const float4* obs4 = (const float4*)(p.observation + (size_t)grow * 1024);
    #pragma unroll 1
    for (int k4 = 0; k4 < 256; ++k4) {
      float4 ov = obs4[k4];
      const float* base = p.W_bq + (200 + 4 * k4) * 200;
      #pragma unroll
      for (int i = 0; i < 7; ++i) if (i < ng) {
        int c4 = g + 8 * i;
        acc[i] = fma4(ov.x, ((const float4*)(base +   0))[c4], acc[i]);
        acc[i] = fma4(ov.y, ((const float4*)(base + 200))[c4], acc[i]);
        acc[i] = fma4(ov.z, ((const float4*)(base + 400))[c4], acc[i]);
        acc[i] = fma4(ov.w, ((const float4*)(base + 600))[c4], acc[i]);
      }
    }
  }
  __syncthreads();                    // all prior-out reads of sH (hp) done
  #pragma unroll
  for (int i = 0; i < 7; ++i) if (i < ng) {
    float4 h = relu4(acc[i]);
    int c = 4 * (g + 8 * i);
    sH[r * PITCH + c + 0] = h.x; sH[r * PITCH + c + 1] = h.y;
    sH[r * PITCH + c + 2] = h.z; sH[r * PITCH + c + 3] = h.w;
  }
  __syncthreads();

  // ---- post_out = relu(hq @ W_sq + b_sq); same eps (jax reuses key 42)
  #pragma unroll
  for (int i = 0; i < 4; ++i) if (i < nm) {
    int m = g + 8 * i;
    ma[i]  = ld4(p.b_sq + 4 * m);
    sa4[i] = ld4(p.b_sq + 4 * (m + 25));
  }
  #pragma unroll 1
  for (int k = 0; k < 200; ++k) {
    float hv = sH[r * PITCH + k];
    const float4* w = (const float4*)(p.W_sq + k * 200);
    #pragma unroll
    for (int i = 0; i < 4; ++i) if (i < nm) {
      int m = g + 8 * i;
      ma[i]  = fma4(hv, w[m],      ma[i]);
      sa4[i] = fma4(hv, w[m + 25], sa4[i]);
    }
  }
  {
    float* out_qs = p.out + (size_t)BATCH * 500;
    float* out_qm = p.out + (size_t)BATCH * 600;
    float* out_qd = p.out + (size_t)BATCH * 700;
    #pragma unroll
    for (int i = 0; i < 4; ++i) if (i < nm) {
      int m = g + 8 * i, c = 4 * m;
      float4 mean = relu4(ma[i]);
      float4 sraw = relu4(sa4[i]);
      float4 sd;
      sd.x = softplusf_(sraw.x) + 0.1f; sd.y = softplusf_(sraw.y) + 0.1f;
      sd.z = softplusf_(sraw.z) + 0.1f; sd.w = softplusf_(sraw.w) + 0.1f;
      float4 st;
      st.x = fmaf(sd.x, eps4[i].x, mean.x); st.y = fmaf(sd.y, eps4[i].y, mean.y);
      st.z = fmaf(sd.z, eps4[i].z, mean.z); st.w = fmaf(sd.w, eps4[i].w, mean.w);
      *(float4*)(out_qs + (size_t)grow * 100 + c) = st;
      *(float4*)(out_qm + (size_t)grow * 100 + c) = mean;
      *(float4*)(out_qd + (size_t)grow * 100 + c) = sd;
    }
  }
}

extern "C" void kernel_launch(void* const* d_in, const int* in_sizes, int n_in,
                              void* d_out, int out_size, void* d_ws, size_t ws_size,
                              hipStream_t stream)
{
  KParams p;
  p.prev_state  = (const float*)d_in[0];
  p.prev_action = (const float*)d_in[1];
  p.prev_belief = (const float*)d_in[2];
  p.observation = (const float*)d_in[3];
  p.nonterm     = (const float*)d_in[4];
  p.W_sa = (const float*)d_in[5];  p.b_sa = (const float*)d_in[6];
  p.W_ir = (const float*)d_in[7];  p.b_ir = (const float*)d_in[8];
  p.W_iz = (const float*)d_in[9];  p.b_iz = (const float*)d_in[10];
  p.W_in = (const float*)d_in[11]; p.b_in = (const float*)d_in[12];
  p.W_hr = (const float*)d_in[13]; p.W_hz = (const float*)d_in[14];
  p.W_hn = (const float*)d_in[15]; p.b_hn = (const float*)d_in[16];
  p.W_bp = (const float*)d_in[17]; p.b_bp = (const float*)d_in[18];
  p.W_sp = (const float*)d_in[19]; p.b_sp = (const float*)d_in[20];
  p.W_bq = (const float*)d_in[21]; p.b_bq = (const float*)d_in[22];
  p.W_sq = (const float*)d_in[23]; p.b_sq = (const float*)d_in[24];
  p.out  = (float*)d_out;
  rssm_fused<<<NBLK, 256, 0, stream>>>(p);
}

// Round 4
// 594.250 us; speedup vs baseline: 6.4432x; 6.4432x over previous
//
#include <hip/hip_runtime.h>
#include <stdint.h>

typedef short short8 __attribute__((ext_vector_type(8)));
typedef float floatx4 __attribute__((ext_vector_type(4)));
typedef unsigned short ushort_t;

#define BATCH 32768
#define STR   232          // LDS row stride in bf16 elems (16 rows per wave slab)
#define SLAB  (16*STR)     // 3712 ushorts = 7424 B per buffer
#define TOT_TILES 1391     // ws need = TOT_TILES * 1024 B = 1.42 MB

// matrix ids (order matches convw src[] and TILE0)
#define M_SA 0
#define M_IR 1
#define M_HR 2
#define M_IZ 3
#define M_HZ 4
#define M_IN 5
#define M_HN 6
#define M_BP 7
#define M_SP 8
#define M_SQ 9
#define M_BQ 10

__device__ constexpr int TILE0[11] = {0,65,156,247,338,429,520,611,702,793,884};
__device__ constexpr int KLIM[11]  = {132,200,200,200,200,200,200,200,200,200,0};

__device__ __forceinline__ ushort_t f2bf(float f){
  uint32_t u = __float_as_uint(f);
  uint32_t r = (u + 0x7fffu + ((u >> 16) & 1u)) >> 16;   // RNE
  return (ushort_t)r;
}
__device__ __forceinline__ float bf2f(ushort_t h){ return __uint_as_float(((uint32_t)h) << 16); }

__device__ __forceinline__ float sigmf_(float x){ return 1.f / (1.f + expf(-x)); }
__device__ __forceinline__ float softplusf_(float x){
  return fmaxf(x, 0.f) + log1pf(expf(-fabsf(x)));
}
__device__ __forceinline__ uint32_t rotl32(uint32_t x, int r){ return (x << r) | (x >> (32 - r)); }

__device__ __forceinline__ void threefry2x32_k42(uint32_t x0, uint32_t x1,
                                                 uint32_t& o0, uint32_t& o1){
  const uint32_t k0 = 0u, k1 = 42u, k2 = 0u ^ 42u ^ 0x1BD11BDAu;
  x0 += k0; x1 += k1;
#define TF_R(rot) { x0 += x1; x1 = rotl32(x1, rot); x1 ^= x0; }
  TF_R(13) TF_R(15) TF_R(26) TF_R(6)  x0 += k1; x1 += k2 + 1u;
  TF_R(17) TF_R(29) TF_R(16) TF_R(24) x0 += k2; x1 += k0 + 2u;
  TF_R(13) TF_R(15) TF_R(26) TF_R(6)  x0 += k0; x1 += k1 + 3u;
  TF_R(17) TF_R(29) TF_R(16) TF_R(24) x0 += k1; x1 += k2 + 4u;
  TF_R(13) TF_R(15) TF_R(26) TF_R(6)  x0 += k2; x1 += k0 + 5u;
#undef TF_R
  o0 = x0; o1 = x1;
}

__device__ __forceinline__ float jax_erfinv(float x){
  float w = -log1pf(-x * x);
  float p;
  if (w < 5.0f) {
    w -= 2.5f;
    p = 2.81022636e-08f;
    p = fmaf(p, w, 3.43273939e-07f);
    p = fmaf(p, w, -3.5233877e-06f);
    p = fmaf(p, w, -4.39150654e-06f);
    p = fmaf(p, w, 0.00021858087f);
    p = fmaf(p, w, -0.00125372503f);
    p = fmaf(p, w, -0.00417768164f);
    p = fmaf(p, w, 0.246640727f);
    p = fmaf(p, w, 1.50140941f);
  } else {
    w = sqrtf(w) - 3.0f;
    p = -0.000200214257f;
    p = fmaf(p, w, 0.000100950558f);
    p = fmaf(p, w, 0.00134934322f);
    p = fmaf(p, w, -0.00367342844f);
    p = fmaf(p, w, 0.00573950773f);
    p = fmaf(p, w, -0.0076224613f);
    p = fmaf(p, w, 0.00943887047f);
    p = fmaf(p, w, 1.00167406f);
    p = fmaf(p, w, 2.83297682f);
  }
  return p * x;
}

// partitionable threefry: counter=(0,j), bits = o0^o1  (verified passing R2)
__device__ __forceinline__ float jax_normal_at(uint32_t j){
  uint32_t o0, o1;
  threefry2x32_k42(0u, j, o0, o1);
  uint32_t bits = o0 ^ o1;
  const float lo = -0.99999994f;
  float f = __uint_as_float((bits >> 9) | 0x3f800000u) - 1.0f;
  float fm = f * 1.99999994f;
  float u = fmaxf(lo, fm + lo);
  return 1.41421356f * jax_erfinv(u);
}

// ---------------- weight conversion kernel (ws path only) ----------------
struct ConvP { const float* src[11]; ushort_t* dst; };

__global__ void __launch_bounds__(64) convw(ConvP cp)
{
  int t = blockIdx.x;
  int lane = threadIdx.x;
  const int cum[12] = {0,65,156,247,338,429,520,611,702,793,884,1391};
  int mi = 0;
  #pragma unroll
  for (int i = 0; i < 11; ++i) if (t >= cum[i+1]) mi = i+1;
  int lt = t - cum[mi];
  int kb = lt / 13, nt = lt - kb*13;
  const float* S = cp.src[mi];
  int q = lane >> 4, m = lane & 15;
  int n = nt*16 + m;
  ushort_t* D = cp.dst + (size_t)t*512 + lane*8;
  #pragma unroll
  for (int j = 0; j < 8; ++j){
    int k = kb*32 + q*8 + j;
    float v = 0.f;
    if (n < 200){
      if (mi == 10){                       // W_bq: k<200 nb rows; 200..223 zero; >=224 obs rows
        if (k < 200) v = S[k*200+n];
        else if (k >= 224) v = S[(size_t)(k-24)*200+n];
      } else {
        int K = (mi == 0) ? 132 : 200;
        if (k < K) v = S[k*200+n];
      }
    }
    D[j] = f2bf(v);
  }
}

// ---------------- main fused kernel ----------------
struct MainP {
  const float* prev_state; const float* prev_action; const float* prev_belief;
  const float* observation; const float* nonterm;
  const float* b_sa; const float* b_ir; const float* b_iz; const float* b_in; const float* b_hn;
  const float* b_bp; const float* b_sp; const float* b_bq; const float* b_sq;
  const float* W[11];          // fp32 weights by mat id (direct path)
  const ushort_t* ws;
  float* out;
};

__device__ __forceinline__ short8 afrag(const ushort_t* buf, int m, int kb, int q){
  return *(const short8*)(buf + m*STR + kb*32 + q*8);
}

// B-fragment: from bf16 ws (WS=1) or built from fp32 weights in-register (WS=0)
template<int MAT, int WS>
__device__ __forceinline__ short8 bfr(const MainP& p, int kb, int nt, int lane, int q, int m){
  if (WS){
    return *(const short8*)(p.ws + (((size_t)(TILE0[MAT] + kb*13 + nt)) << 9) + (lane << 3));
  } else {
    int n = nt*16 + m;
    const float* S = p.W[MAT];
    uint32_t u[8];
    #pragma unroll
    for (int j = 0; j < 8; ++j){
      int k = kb*32 + q*8 + j;
      int srow;
      if (MAT == M_BQ) srow = (k < 200) ? k : ((k >= 224) ? k - 24 : -1);
      else             srow = (k < KLIM[MAT]) ? k : -1;
      float v = (srow >= 0 && n < 200) ? S[(size_t)srow*200 + n] : 0.f;
      u[j] = __float_as_uint(v);
    }
    short8 r;
    #pragma unroll
    for (int j = 0; j < 8; ++j) r[j] = (short)(u[j] >> 16);  // truncate to bf16
    return r;
  }
}

// GRU column-chunk: 4 accumulator streams for CNT tiles; gates; writes nb to HBM ONLY
// (bufX must stay intact for the other chunk's A-frag reads).
template<int WS, int CNT, int NT0>
__device__ __forceinline__ void gru_chunk(const MainP& p,
    const ushort_t* bufX, const ushort_t* bufH, int R0, int m, int q, int lane)
{
  floatx4 aR[CNT], aZ[CNT], aXN[CNT], aHN[CNT];
  #pragma unroll
  for (int i = 0; i < CNT; ++i){
    int col = (NT0+i)*16 + m;
    float br = (col<200)? p.b_ir[col] : 0.f;
    float bz = (col<200)? p.b_iz[col] : 0.f;
    float bn = (col<200)? p.b_in[col] : 0.f;
    float bh = (col<200)? p.b_hn[col] : 0.f;
    aR[i]  = (floatx4){br,br,br,br};
    aZ[i]  = (floatx4){bz,bz,bz,bz};
    aXN[i] = (floatx4){bn,bn,bn,bn};
    aHN[i] = (floatx4){bh,bh,bh,bh};
  }
  #pragma unroll 1
  for (int kb = 0; kb < 7; ++kb){
    short8 ax = afrag(bufX, m, kb, q);
    short8 ah = afrag(bufH, m, kb, q);
    #pragma unroll
    for (int i = 0; i < CNT; ++i){
      int nt = NT0 + i;
      aR[i]  = __builtin_amdgcn_mfma_f32_16x16x32_bf16(ax, bfr<M_IR,WS>(p,kb,nt,lane,q,m), aR[i], 0,0,0);
      aR[i]  = __builtin_amdgcn_mfma_f32_16x16x32_bf16(ah, bfr<M_HR,WS>(p,kb,nt,lane,q,m), aR[i], 0,0,0);
      aZ[i]  = __builtin_amdgcn_mfma_f32_16x16x32_bf16(ax, bfr<M_IZ,WS>(p,kb,nt,lane,q,m), aZ[i], 0,0,0);
      aZ[i]  = __builtin_amdgcn_mfma_f32_16x16x32_bf16(ah, bfr<M_HZ,WS>(p,kb,nt,lane,q,m), aZ[i], 0,0,0);
      aXN[i] = __builtin_amdgcn_mfma_f32_16x16x32_bf16(ax, bfr<M_IN,WS>(p,kb,nt,lane,q,m), aXN[i], 0,0,0);
      aHN[i] = __builtin_amdgcn_mfma_f32_16x16x32_bf16(ah, bfr<M_HN,WS>(p,kb,nt,lane,q,m), aHN[i], 0,0,0);
    }
  }
  #pragma unroll
  for (int i = 0; i < CNT; ++i){
    int col = (NT0+i)*16 + m;
    if (col < 200){
      #pragma unroll
      for (int rg = 0; rg < 4; ++rg){
        int rowl = q*4 + rg;
        float rr = sigmf_(aR[i][rg]);
        float zz = sigmf_(aZ[i][rg]);
        float nn = tanhf(fmaf(rr, aHN[i][rg], aXN[i][rg]));
        float hv = bf2f(bufH[rowl*STR + col]);
        float nb = fmaf(zz, hv - nn, nn);
        p.out[(size_t)(R0+rowl)*200 + col] = nb;
      }
    }
  }
}

// head epilogue (verified passing R3 for prior): std transposed via fp32 LDS scratch
__device__ __forceinline__ void head_out(const floatx4* acc, float* sdb,
    float* o_state, float* o_mean, float* o_std, int R0, int m, int q)
{
  #pragma unroll
  for (int nt = 6; nt < 13; ++nt){
    int col = nt*16 + m;
    if (col >= 100 && col < 200){
      #pragma unroll
      for (int rg = 0; rg < 4; ++rg){
        int rowl = q*4 + rg;
        float sr = fmaxf(acc[nt][rg], 0.f);
        float sd = softplusf_(sr) + 0.1f;
        sdb[rowl*100 + (col-100)] = sd;
        o_std[(size_t)(R0+rowl)*100 + (col-100)] = sd;
      }
    }
  }
  __syncthreads();
  #pragma unroll
  for (int nt = 0; nt < 7; ++nt){
    int col = nt*16 + m;
    if (col < 100){
      #pragma unroll
      for (int rg = 0; rg < 4; ++rg){
        int rowl = q*4 + rg;
        float mean = fmaxf(acc[nt][rg], 0.f);
        float sd = sdb[rowl*100 + col];
        float e = jax_normal_at((uint32_t)(R0+rowl)*100u + (uint32_t)col);
        o_mean[(size_t)(R0+rowl)*100 + col] = mean;
        o_state[(size_t)(R0+rowl)*100 + col] = fmaf(sd, e, mean);
      }
    }
  }
  __syncthreads();
}

template<int WS>
__global__ void __launch_bounds__(256, 2) rssm_mfma(MainP p)
{
  __shared__ __align__(16) ushort_t lds[4 * 2 * SLAB];

  const int tid  = threadIdx.x;
  const int w    = tid >> 6;
  const int lane = tid & 63;
  const int q    = lane >> 4;
  const int m    = lane & 15;
  const int R0   = blockIdx.x * 64 + w * 16;

  ushort_t* bufX = lds + w * 2 * SLAB;
  ushort_t* bufH = bufX + SLAB;

  // ---- phase 1: stage [s*nt | a | 0] -> bufX (k 0..159); zero bufH pad cols
  for (int t = lane; t < 16*160; t += 64){
    int rr = t / 160, cc = t - rr*160;
    int grow = R0 + rr;
    float v = 0.f;
    if (cc < 100)      v = p.prev_state[(size_t)grow*100 + cc] * p.nonterm[grow];
    else if (cc < 132) v = p.prev_action[(size_t)grow*32 + (cc-100)];
    bufX[rr*STR + cc] = f2bf(v);
  }
  for (int t = lane; t < 16*24; t += 64){
    int rr = t / 24, cc = 200 + (t - rr*24);
    bufH[rr*STR + cc] = 0;
  }
  __syncthreads();

  // ---- phase 2: SA gemm -> h (relu) -> bufH
  {
    floatx4 acc[13];
    #pragma unroll
    for (int nt = 0; nt < 13; ++nt){
      int col = nt*16 + m;
      float bv = (col<200)? p.b_sa[col] : 0.f;
      acc[nt] = (floatx4){bv,bv,bv,bv};
    }
    #pragma unroll 1
    for (int kb = 0; kb < 5; ++kb){
      short8 a = afrag(bufX, m, kb, q);
      #pragma unroll
      for (int nt = 0; nt < 13; ++nt)
        acc[nt] = __builtin_amdgcn_mfma_f32_16x16x32_bf16(a, bfr<M_SA,WS>(p,kb,nt,lane,q,m), acc[nt], 0,0,0);
    }
    #pragma unroll
    for (int nt = 0; nt < 13; ++nt){
      int col = nt*16 + m;
      if (col < 200){
        #pragma unroll
        for (int rg = 0; rg < 4; ++rg)
          bufH[(q*4+rg)*STR + col] = f2bf(fmaxf(acc[nt][rg], 0.f));
      }
    }
  }

  // ---- phase 3: stage x = prev_belief -> bufX (zero pad to 223)
  for (int t = lane; t < 16*224; t += 64){
    int rr = t / 224, cc = t - rr*224;
    float v = (cc < 200) ? p.prev_belief[(size_t)(R0+rr)*224 - (size_t)(R0+rr)*24 + cc] : 0.f; // = *200
    bufX[rr*STR + cc] = f2bf(v);
  }
  __syncthreads();

  // ---- phase 4: GRU (two column chunks; nb goes to HBM only)
  gru_chunk<WS,7,0>(p, bufX, bufH, R0, m, q, lane);
  gru_chunk<WS,6,7>(p, bufX, bufH, R0, m, q, lane);
  __syncthreads();   // drains vmcnt(0): nb stores visible in L2

  // ---- re-stage nb from out -> bufX (bf16, zero pads)
  for (int t = lane; t < 16*224; t += 64){
    int rr = t / 224, cc = t - rr*224;
    float v = (cc < 200) ? p.out[(size_t)(R0+rr)*200 + cc] : 0.f;
    bufX[rr*STR + cc] = f2bf(v);
  }
  __syncthreads();

  // ---- phase 5: bp gemm -> hp -> bufH
  {
    floatx4 acc[13];
    #pragma unroll
    for (int nt = 0; nt < 13; ++nt){
      int col = nt*16 + m;
      float bv = (col<200)? p.b_bp[col] : 0.f;
      acc[nt] = (floatx4){bv,bv,bv,bv};
    }
    #pragma unroll 1
    for (int kb = 0; kb < 7; ++kb){
      short8 a = afrag(bufX, m, kb, q);
      #pragma unroll
      for (int nt = 0; nt < 13; ++nt)
        acc[nt] = __builtin_amdgcn_mfma_f32_16x16x32_bf16(a, bfr<M_BP,WS>(p,kb,nt,lane,q,m), acc[nt], 0,0,0);
    }
    #pragma unroll
    for (int nt = 0; nt < 13; ++nt){
      int col = nt*16 + m;
      if (col < 200){
        #pragma unroll
        for (int rg = 0; rg < 4; ++rg)
          bufH[(q*4+rg)*STR + col] = f2bf(fmaxf(acc[nt][rg], 0.f));
      }
    }
  }
  __syncthreads();

  // ---- phase 6: sp gemm -> prior outputs (fp32 scratch in bufH)
  {
    floatx4 acc[13];
    #pragma unroll
    for (int nt = 0; nt < 13; ++nt){
      int col = nt*16 + m;
      float bv = (col<200)? p.b_sp[col] : 0.f;
      acc[nt] = (floatx4){bv,bv,bv,bv};
    }
    #pragma unroll 1
    for (int kb = 0; kb < 7; ++kb){
      short8 a = afrag(bufH, m, kb, q);
      #pragma unroll
      for (int nt = 0; nt < 13; ++nt)
        acc[nt] = __builtin_amdgcn_mfma_f32_16x16x32_bf16(a, bfr<M_SP,WS>(p,kb,nt,lane,q,m), acc[nt], 0,0,0);
    }
    head_out(acc, (float*)bufH,
             p.out + (size_t)BATCH*200, p.out + (size_t)BATCH*300, p.out + (size_t)BATCH*400,
             R0, m, q);
  }

  // ---- phase 7: hq gemm (nb A-frags from bufX, obs streamed from HBM)
  {
    floatx4 acc[13];
    #pragma unroll
    for (int nt = 0; nt < 13; ++nt){
      int col = nt*16 + m;
      float bv = (col<200)? p.b_bq[col] : 0.f;
      acc[nt] = (floatx4){bv,bv,bv,bv};
    }
    #pragma unroll 1
    for (int kb = 0; kb < 7; ++kb){
      short8 a = afrag(bufX, m, kb, q);
      #pragma unroll
      for (int nt = 0; nt < 13; ++nt)
        acc[nt] = __builtin_amdgcn_mfma_f32_16x16x32_bf16(a, bfr<M_BQ,WS>(p,kb,nt,lane,q,m), acc[nt], 0,0,0);
    }
    const float* orow_base = p.observation + (size_t)(R0+m)*1024;
    #pragma unroll 1
    for (int kb = 7; kb < 39; ++kb){
      const float* orow = orow_base + (kb*32 - 224) + q*8;
      float4 o1 = *(const float4*)(orow);
      float4 o2 = *(const float4*)(orow + 4);
      short8 ao;
      ao[0] = (short)f2bf(o1.x); ao[1] = (short)f2bf(o1.y);
      ao[2] = (short)f2bf(o1.z); ao[3] = (short)f2bf(o1.w);
      ao[4] = (short)f2bf(o2.x); ao[5] = (short)f2bf(o2.y);
      ao[6] = (short)f2bf(o2.z); ao[7] = (short)f2bf(o2.w);
      #pragma unroll
      for (int nt = 0; nt < 13; ++nt)
        acc[nt] = __builtin_amdgcn_mfma_f32_16x16x32_bf16(ao, bfr<M_BQ,WS>(p,kb,nt,lane,q,m), acc[nt], 0,0,0);
    }
    // hq -> bufH + re-zero pad cols (phase-6 scratch clobbered them; avoids NaN A-pads)
    #pragma unroll
    for (int nt = 0; nt < 13; ++nt){
      int col = nt*16 + m;
      if (col < 200){
        #pragma unroll
        for (int rg = 0; rg < 4; ++rg)
          bufH[(q*4+rg)*STR + col] = f2bf(fmaxf(acc[nt][rg], 0.f));
      }
    }
    for (int t = lane; t < 16*24; t += 64){
      int rr = t / 24, cc = 200 + (t - rr*24);
      bufH[rr*STR + cc] = 0;
    }
  }
  __syncthreads();

  // ---- phase 8: sq gemm -> posterior outputs (same eps; fp32 scratch in bufX)
  {
    floatx4 acc[13];
    #pragma unroll
    for (int nt = 0; nt < 13; ++nt){
      int col = nt*16 + m;
      float bv = (col<200)? p.b_sq[col] : 0.f;
      acc[nt] = (floatx4){bv,bv,bv,bv};
    }
    #pragma unroll 1
    for (int kb = 0; kb < 7; ++kb){
      short8 a = afrag(bufH, m, kb, q);
      #pragma unroll
      for (int nt = 0; nt < 13; ++nt)
        acc[nt] = __builtin_amdgcn_mfma_f32_16x16x32_bf16(a, bfr<M_SQ,WS>(p,kb,nt,lane,q,m), acc[nt], 0,0,0);
    }
    head_out(acc, (float*)bufX,
             p.out + (size_t)BATCH*500, p.out + (size_t)BATCH*600, p.out + (size_t)BATCH*700,
             R0, m, q);
  }
}

extern "C" void kernel_launch(void* const* d_in, const int* in_sizes, int n_in,
                              void* d_out, int out_size, void* d_ws, size_t ws_size,
                              hipStream_t stream)
{
  MainP p;
  p.prev_state  = (const float*)d_in[0];
  p.prev_action = (const float*)d_in[1];
  p.prev_belief = (const float*)d_in[2];
  p.observation = (const float*)d_in[3];
  p.nonterm     = (const float*)d_in[4];
  p.b_sa = (const float*)d_in[6];
  p.b_ir = (const float*)d_in[8];
  p.b_iz = (const float*)d_in[10];
  p.b_in = (const float*)d_in[12];
  p.b_hn = (const float*)d_in[16];
  p.b_bp = (const float*)d_in[18];
  p.b_sp = (const float*)d_in[20];
  p.b_bq = (const float*)d_in[22];
  p.b_sq = (const float*)d_in[24];
  p.W[M_SA] = (const float*)d_in[5];
  p.W[M_IR] = (const float*)d_in[7];
  p.W[M_HR] = (const float*)d_in[13];
  p.W[M_IZ] = (const float*)d_in[9];
  p.W[M_HZ] = (const float*)d_in[14];
  p.W[M_IN] = (const float*)d_in[11];
  p.W[M_HN] = (const float*)d_in[15];
  p.W[M_BP] = (const float*)d_in[17];
  p.W[M_SP] = (const float*)d_in[19];
  p.W[M_SQ] = (const float*)d_in[23];
  p.W[M_BQ] = (const float*)d_in[21];
  p.ws   = (const ushort_t*)d_ws;
  p.out  = (float*)d_out;

  bool use_ws = (ws_size >= (size_t)TOT_TILES * 1024u);
  if (use_ws){
    ConvP cp;
    cp.src[0]  = p.W[M_SA]; cp.src[1]  = p.W[M_IR]; cp.src[2]  = p.W[M_HR];
    cp.src[3]  = p.W[M_IZ]; cp.src[4]  = p.W[M_HZ]; cp.src[5]  = p.W[M_IN];
    cp.src[6]  = p.W[M_HN]; cp.src[7]  = p.W[M_BP]; cp.src[8]  = p.W[M_SP];
    cp.src[9]  = p.W[M_SQ]; cp.src[10] = p.W[M_BQ];
    cp.dst     = (ushort_t*)d_ws;
    convw<<<TOT_TILES, 64, 0, stream>>>(cp);
    rssm_mfma<1><<<512, 256, 0, stream>>>(p);
  } else {
    rssm_mfma<0><<<512, 256, 0, stream>>>(p);
  }
}